// Round 8
// baseline (137.091 us; speedup 1.0000x reference)
//
#include <hip/hip_runtime.h>

// CenterLoss: loss = mean_b clip(||x_b - centers[labels[b]]||^2, 1e-12, 1e12)
//             + (C-1)*1e-12   (faithful replication of clipping the masked zeros)
//
// x: (8192,2048) f32   labels: (8192,) int   centers: (4096,2048) f32   out: scalar
//
// SINGLE kernel, single graph node. One wave per sample (proven R2 engine:
// 128 MB logical traffic at ~6.6 TB/s = fabric ceiling; R3/R4 restructurings
// were nulls). Finalize fused via MODULAR exit ticket: NBLK=2048 divides 2^32,
// so ((pos & (NBLK-1)) == NBLK-1) fires exactly once per call regardless of
// the counter's accumulated value -> no memset, graph-replay deterministic.
//
// Traffic model (R1-R7): x = 64 MB from HBM (L3 flushed by harness poison
// fills), centers = 64 MB gathered from L3 (21 MB unique doesn't fit per-XCD
// L2). L3-hits and HBM share the ~6.9 TB/s memory-side fabric.

#define BATCH 8192
#define FEAT  2048
#define NCLS  4096
#define BLK   256
#define WAVES_PER_BLK (BLK / 64)              // 4
#define NBLK (BATCH / WAVES_PER_BLK)          // 2048 (power of two!)

// d_ws layout: [0] ticket (never reset; modular test)  [1..3] pad
//              [4 ..) part[BATCH] floats (fully overwritten every call)
#define OFF_PART 4

__global__ void __launch_bounds__(BLK)
cl_all(const float* __restrict__ x,
       const int* __restrict__ labels,
       const float* __restrict__ centers,
       float* __restrict__ out,
       int* __restrict__ wsi) {
    const int tid  = threadIdx.x;
    const int wid  = tid >> 6;
    const int lane = tid & 63;
    const int b    = blockIdx.x * WAVES_PER_BLK + wid;   // sample for this wave

    float* __restrict__ part = (float*)(wsi + OFF_PART);

    const int lbl = labels[b];                           // wave-uniform

    const float4* __restrict__ xr =
        reinterpret_cast<const float4*>(x + (size_t)b * FEAT);
    const float4* __restrict__ cr =
        reinterpret_cast<const float4*>(centers + (size_t)lbl * FEAT);

    float acc0 = 0.0f, acc1 = 0.0f;
#pragma unroll
    for (int j = 0; j < FEAT / 4 / 64; ++j) {            // 8 iterations
        const int idx = lane + j * 64;
        const float4 xv = xr[idx];
        const float4 cv = cr[idx];
        const float d0 = xv.x - cv.x;
        const float d1 = xv.y - cv.y;
        const float d2 = xv.z - cv.z;
        const float d3 = xv.w - cv.w;
        acc0 += d0 * d0 + d1 * d1;
        acc1 += d2 * d2 + d3 * d3;
    }
    float acc = acc0 + acc1;

    // wave (64-lane) reduction
#pragma unroll
    for (int off = 32; off > 0; off >>= 1)
        acc += __shfl_down(acc, off, 64);

    if (lane == 0) {
        // per-sample clip; direct per-wave store
        part[b] = fminf(fmaxf(acc, 1e-12f), 1e12f);
    }

    // ---------------- modular exit-ticket finalize ----------------
    __shared__ int   sticket;
    __shared__ float sred[WAVES_PER_BLK];

    __syncthreads();
    if (tid == 0) {
        __builtin_amdgcn_fence(__ATOMIC_RELEASE, "agent");
        sticket = __hip_atomic_fetch_add(&wsi[0], 1, __ATOMIC_ACQ_REL,
                                         __HIP_MEMORY_SCOPE_AGENT);
    }
    __syncthreads();

    if ((sticket & (NBLK - 1)) == NBLK - 1) {            // last block, any epoch
        __builtin_amdgcn_fence(__ATOMIC_ACQUIRE, "agent");
        const float4* __restrict__ pr = reinterpret_cast<const float4*>(part);
        float facc = 0.0f;
#pragma unroll
        for (int j = 0; j < BATCH / 4 / BLK; ++j) {      // 8 iterations
            const float4 v = pr[tid + j * BLK];
            facc += (v.x + v.y) + (v.z + v.w);
        }
#pragma unroll
        for (int off = 32; off > 0; off >>= 1)
            facc += __shfl_down(facc, off, 64);
        if (lane == 0) sred[wid] = facc;
        __syncthreads();
        if (tid == 0) {
            const float total = sred[0] + sred[1] + sred[2] + sred[3];
            // masked-zero entries: (BATCH*NCLS - BATCH) * 1e-12 / BATCH
            out[0] = total / (float)BATCH + (float)(NCLS - 1) * 1e-12f;
        }
    }
}

extern "C" void kernel_launch(void* const* d_in, const int* in_sizes, int n_in,
                              void* d_out, int out_size, void* d_ws, size_t ws_size,
                              hipStream_t stream) {
    const float* x       = (const float*)d_in[0];
    const int*   labels  = (const int*)d_in[1];
    const float* centers = (const float*)d_in[2];
    float* out = (float*)d_out;
    int*   wsi = (int*)d_ws;

    cl_all<<<NBLK, BLK, 0, stream>>>(x, labels, centers, out, wsi);
}

// Round 9
// 43.965 us; speedup vs baseline: 3.1182x; 3.1182x over previous
//
#include <hip/hip_runtime.h>

// CenterLoss: loss = mean_b clip(||x_b - centers[labels[b]]||^2, 1e-12, 1e12)
//             + (C-1)*1e-12   (faithful replication of clipping the masked zeros)
//
// x: (8192,2048) f32   labels: (8192,) int   centers: (4096,2048) f32   out: scalar
//
// Structure: 4-byte memset of d_out + ONE kernel.
//   - one wave per sample (R2 engine: 128 MB logical at ~6.6 TB/s fabric
//     ceiling; R3/R4 MLP+pipeline restructurings were exact nulls)
//   - 4 waves LDS-reduce to one float; ONE device-scope atomicAdd per block
//     (2048 total, staggered by block completion -> only the tail serializes;
//     R1 precedent: FP atomic accumulation passed with absmax 0.0)
//   - block 0 adds the (C-1)*1e-12 clip constant
//
// R8 lessons: no per-block agent fences (L2-writeback disaster, 202 us), no
// modular exit ticket (0xAA poison => counter !≡ 0 mod NBLK => fired early,
// absmax 48). atomicAdd needs no explicit fencing and d_out is memset to 0
// every call, so every replay does identical work on identical state.

#define BATCH 8192
#define FEAT  2048
#define NCLS  4096
#define BLK   256
#define WAVES_PER_BLK (BLK / 64)              // 4
#define NBLK (BATCH / WAVES_PER_BLK)          // 2048

__global__ void __launch_bounds__(BLK)
cl_all(const float* __restrict__ x,
       const int* __restrict__ labels,
       const float* __restrict__ centers,
       float* __restrict__ out) {
    const int tid  = threadIdx.x;
    const int wid  = tid >> 6;
    const int lane = tid & 63;
    const int b    = blockIdx.x * WAVES_PER_BLK + wid;   // sample for this wave

    const int lbl = labels[b];                           // wave-uniform

    const float4* __restrict__ xr =
        reinterpret_cast<const float4*>(x + (size_t)b * FEAT);
    const float4* __restrict__ cr =
        reinterpret_cast<const float4*>(centers + (size_t)lbl * FEAT);

    float acc0 = 0.0f, acc1 = 0.0f;
#pragma unroll
    for (int j = 0; j < FEAT / 4 / 64; ++j) {            // 8 iterations
        const int idx = lane + j * 64;
        const float4 xv = xr[idx];
        const float4 cv = cr[idx];
        const float d0 = xv.x - cv.x;
        const float d1 = xv.y - cv.y;
        const float d2 = xv.z - cv.z;
        const float d3 = xv.w - cv.w;
        acc0 += d0 * d0 + d1 * d1;
        acc1 += d2 * d2 + d3 * d3;
    }
    float acc = acc0 + acc1;

    // wave (64-lane) reduction
#pragma unroll
    for (int off = 32; off > 0; off >>= 1)
        acc += __shfl_down(acc, off, 64);

    // per-sample clip, then block reduction across the 4 waves
    __shared__ float s[WAVES_PER_BLK];
    if (lane == 0)
        s[wid] = fminf(fmaxf(acc, 1e-12f), 1e12f);
    __syncthreads();

    if (tid == 0) {
        float v = (s[0] + s[1] + s[2] + s[3]) * (1.0f / (float)BATCH);
        if (blockIdx.x == 0)
            v += (float)(NCLS - 1) * 1e-12f;   // masked-zero clip constant
        atomicAdd(out, v);                      // one atomic per block (2048)
    }
}

extern "C" void kernel_launch(void* const* d_in, const int* in_sizes, int n_in,
                              void* d_out, int out_size, void* d_ws, size_t ws_size,
                              hipStream_t stream) {
    const float* x       = (const float*)d_in[0];
    const int*   labels  = (const int*)d_in[1];
    const float* centers = (const float*)d_in[2];
    float* out = (float*)d_out;

    (void)hipMemsetAsync(d_out, 0, sizeof(float), stream);
    cl_all<<<NBLK, BLK, 0, stream>>>(x, labels, centers, out);
}

// Round 10
// 33.780 us; speedup vs baseline: 4.0583x; 1.3015x over previous
//
#include <hip/hip_runtime.h>

// CenterLoss: loss = mean_b clip(||x_b - centers[labels[b]]||^2, 1e-12, 1e12)
//             + (C-1)*1e-12   (faithful replication of clipping the masked zeros)
//
// x: (8192,2048) f32   labels: (8192,) int   centers: (4096,2048) f32   out: scalar
//
// Structure: 32 KB memset of part[] + ONE kernel (2049 blocks).
//   - blocks 1..2048: proven R2 engine, one wave per sample, plain store of
//     the clipped per-sample distance into part[b] (always >= 1e-12 > 0).
//   - block 0: spinner-finalizer. Polls part[] with RELAXED agent-scope
//     atomic loads (data-as-flag: value nonzero <=> worker done) -> zero
//     fences, zero same-address RMWs. Sums, writes the scalar.
//
// Hard-won constraints honored here:
//   R8: no per-block agent release fences (L2-writeback serialization, 202us)
//   R8: no modular tickets (0xAA poison breaks epoch alignment)
//   R9: no per-block same-address RMW at 2048 blocks (~10ns each, bunched
//       tail ~20us because all waves complete together)
//   R1-R4: engine is fabric-bound at ~6.6 TB/s on 128 MB logical traffic;
//       MLP/pipeline restructurings are nulls. Keep the engine untouched.

#define BATCH 8192
#define FEAT  2048
#define NCLS  4096
#define BLK   256
#define WAVES_PER_BLK (BLK / 64)              // 4
#define NWBLK (BATCH / WAVES_PER_BLK)         // 2048 worker blocks
#define NBLK  (NWBLK + 1)                     // + spinner block 0
#define PER_THREAD (BATCH / BLK)              // 32 part[] entries per spinner thread

__global__ void __launch_bounds__(BLK)
cl_all(const float* __restrict__ x,
       const int* __restrict__ labels,
       const float* __restrict__ centers,
       float* __restrict__ out,
       float* __restrict__ part) {
    const int tid  = threadIdx.x;
    const int wid  = tid >> 6;
    const int lane = tid & 63;
    const int bid  = blockIdx.x;

    __shared__ float s[WAVES_PER_BLK];

    if (bid == 0) {
        // ---------- spinner-finalizer ----------
        float acc = 0.0f;
#pragma unroll 1
        for (int k = 0; k < PER_THREAD; ++k) {
            const int i = tid + k * BLK;
            float v;
            while ((v = __hip_atomic_load(&part[i], __ATOMIC_RELAXED,
                                          __HIP_MEMORY_SCOPE_AGENT)) == 0.0f) {
                __builtin_amdgcn_s_sleep(32);     // ~2k cycles between polls
            }
            acc += v;                              // datum is its own flag
        }
#pragma unroll
        for (int off = 32; off > 0; off >>= 1)
            acc += __shfl_down(acc, off, 64);
        if (lane == 0) s[wid] = acc;
        __syncthreads();
        if (tid == 0) {
            const float total = s[0] + s[1] + s[2] + s[3];
            // masked-zero entries: (BATCH*NCLS - BATCH) * 1e-12 / BATCH
            out[0] = total / (float)BATCH + (float)(NCLS - 1) * 1e-12f;
        }
        return;
    }

    // ---------- worker: one wave per sample (unchanged R2 engine) ----------
    const int b   = (bid - 1) * WAVES_PER_BLK + wid;
    const int lbl = labels[b];                           // wave-uniform

    const float4* __restrict__ xr =
        reinterpret_cast<const float4*>(x + (size_t)b * FEAT);
    const float4* __restrict__ cr =
        reinterpret_cast<const float4*>(centers + (size_t)lbl * FEAT);

    float acc0 = 0.0f, acc1 = 0.0f;
#pragma unroll
    for (int j = 0; j < FEAT / 4 / 64; ++j) {            // 8 iterations
        const int idx = lane + j * 64;
        const float4 xv = xr[idx];
        const float4 cv = cr[idx];
        const float d0 = xv.x - cv.x;
        const float d1 = xv.y - cv.y;
        const float d2 = xv.z - cv.z;
        const float d3 = xv.w - cv.w;
        acc0 += d0 * d0 + d1 * d1;
        acc1 += d2 * d2 + d3 * d3;
    }
    float acc = acc0 + acc1;

    // wave (64-lane) reduction
#pragma unroll
    for (int off = 32; off > 0; off >>= 1)
        acc += __shfl_down(acc, off, 64);

    if (lane == 0) {
        // per-sample clip; plain store (value >= 1e-12, so nonzero == done)
        part[b] = fminf(fmaxf(acc, 1e-12f), 1e12f);
    }
}

extern "C" void kernel_launch(void* const* d_in, const int* in_sizes, int n_in,
                              void* d_out, int out_size, void* d_ws, size_t ws_size,
                              hipStream_t stream) {
    const float* x       = (const float*)d_in[0];
    const int*   labels  = (const int*)d_in[1];
    const float* centers = (const float*)d_in[2];
    float* out  = (float*)d_out;
    float* part = (float*)d_ws;   // 8192 floats, zeroed below, then overwritten

    (void)hipMemsetAsync(d_ws, 0, BATCH * sizeof(float), stream);
    cl_all<<<NBLK, BLK, 0, stream>>>(x, labels, centers, out, part);
}